// Round 1
// baseline (8789.118 us; speedup 1.0000x reference)
//
#include <hip/hip_runtime.h>
#include <math.h>

// ---------------- constants ----------------
#define T_STEPS 191      // 200 - 9
#define NB 30
#define NB1 31
#define F_DIM 4096
#define HID 256
#define COR 32
#define YS 13            // y feature stride: track(1)+coords(4)+label(1)+conf(1)+dist(6)

__device__ __forceinline__ float sigmoid_(float x) { return 1.f / (1.f + expf(-x)); }

// ---------------- tiled fp32 GEMM: C = act(A @ B + bias) ----------------
// A: M x K (row major) or gathered from rgb when GATHER; B: K x N row major.
template <bool GATHER, bool RELU>
__global__ __launch_bounds__(256) void gemm_tiled(
    const float* __restrict__ A, const float* __restrict__ B,
    const float* __restrict__ bias, float* __restrict__ C,
    int M, int N, int K)
{
    __shared__ float As[16][65];
    __shared__ float Bs[16][65];
    const int tid = threadIdx.x;
    const int tm = tid >> 4, tn = tid & 15;
    const int rowBase = blockIdx.y * 64;
    const int colBase = blockIdx.x * 64;
    float acc[4][4] = {};
    for (int kt = 0; kt < K; kt += 16) {
        #pragma unroll
        for (int l = 0; l < 4; ++l) {
            const int idx = tid + l * 256;
            const int kk = idx & 15, rr = idx >> 4;
            const int row = rowBase + rr;
            float v = 0.f;
            if (row < M) {
                if (GATHER) {
                    // comb[m,k]: m=(t,i); k<256 -> rgb[t, i+1, k]; else rgb[t, 0, k-256]
                    const int t = row / 30, i = row - t * 30;
                    const int k = kt + kk;
                    const int src = (k < 256) ? ((t * NB1 + i + 1) * 256 + k)
                                              : (t * NB1 * 256 + (k - 256));
                    v = A[src];
                } else {
                    v = A[(size_t)row * K + kt + kk];
                }
            }
            As[kk][rr] = v;
            const int nn = idx & 63, k2 = idx >> 6;
            Bs[k2][nn] = B[(size_t)(kt + k2) * N + colBase + nn];
        }
        __syncthreads();
        #pragma unroll
        for (int kk = 0; kk < 16; ++kk) {
            float a[4], b[4];
            #pragma unroll
            for (int i = 0; i < 4; ++i) a[i] = As[kk][tm * 4 + i];
            #pragma unroll
            for (int j = 0; j < 4; ++j) b[j] = Bs[kk][tn * 4 + j];
            #pragma unroll
            for (int i = 0; i < 4; ++i)
                #pragma unroll
                for (int j = 0; j < 4; ++j)
                    acc[i][j] = fmaf(a[i], b[j], acc[i][j]);
        }
        __syncthreads();
    }
    #pragma unroll
    for (int i = 0; i < 4; ++i) {
        const int row = rowBase + tm * 4 + i;
        if (row < M) {
            #pragma unroll
            for (int j = 0; j < 4; ++j) {
                const int col = colBase + tn * 4 + j;
                float v = acc[i][j] + bias[col];
                if (RELU) v = fmaxf(v, 0.f);
                C[(size_t)row * N + col] = v;
            }
        }
    }
}

// ---------------- per-(t,obj) small precompute ----------------
// bfeat -> (pbox_b, logit_b);  dfeat -> xc -> gx_c
__global__ __launch_bounds__(256) void precomp_kernel(
    const float* __restrict__ y,
    const float* __restrict__ Wbb, const float* __restrict__ bbb,
    const float* __restrict__ Wdd, const float* __restrict__ bdd,
    const float* __restrict__ Wproj, const float* __restrict__ bproj,
    const float* __restrict__ Wxc, const float* __restrict__ bxc,
    const float* __restrict__ Wpbox, const float* __restrict__ bpbox,
    const float* __restrict__ Wout, const float* __restrict__ bout,
    float* __restrict__ gxc, float* __restrict__ pbox_b, float* __restrict__ logit_b)
{
    const int m = blockIdx.x;   // t*30+i, t in [0,191)
    const int tid = threadIdx.x;
    __shared__ float bf[256], df[256], xcs[32], yl[16];
    if (tid < YS) yl[tid] = y[m * YS + tid];
    __syncthreads();
    const float invnorm[4] = {1.f/1920.f, 1.f/1200.f, 1.f/1920.f, 1.f/1200.f};
    {
        float s = bbb[tid];
        s = fmaf(yl[1] * invnorm[0], Wbb[0 * 256 + tid], s);
        s = fmaf(yl[2] * invnorm[1], Wbb[1 * 256 + tid], s);
        s = fmaf(yl[3] * invnorm[2], Wbb[2 * 256 + tid], s);
        s = fmaf(yl[4] * invnorm[3], Wbb[3 * 256 + tid], s);
        s = fmaf(yl[6],              Wbb[4 * 256 + tid], s);
        bf[tid] = fmaxf(s, 0.f);
    }
    {
        float s = bdd[tid];
        #pragma unroll
        for (int k = 0; k < 6; ++k) s = fmaf(yl[7 + k], Wdd[k * 256 + tid], s);
        df[tid] = fmaxf(s, 0.f);
    }
    __syncthreads();
    if (tid < 32) {
        float s = bproj[tid];
        for (int k = 0; k < 256; ++k) s = fmaf(df[k], Wproj[k * 32 + tid], s);
        xcs[tid] = s;
    }
    __syncthreads();
    if (tid < 96) {
        float s = bxc[tid];
        #pragma unroll
        for (int k = 0; k < 32; ++k) s = fmaf(xcs[k], Wxc[k * 96 + tid], s);
        gxc[m * 96 + tid] = s;
    }
    if (tid >= 128 && tid < 164) {
        const int c = tid - 128;
        float s = bpbox[c];
        for (int k = 0; k < 256; ++k) s = fmaf(bf[k], Wpbox[(256 + k) * 36 + c], s);
        pbox_b[m * 36 + c] = s;
    }
    if (tid == 192) {
        float s = bout[0];
        for (int k = 0; k < 256; ++k) s = fmaf(bf[k], Wout[256 + k], s);
        logit_b[m] = s;
    }
}

// ---------------- sequential recurrence: 30 persistent blocks, 1 barrier/step ----------------
__device__ __forceinline__ void softmax30(const float* s, float* w) {
    float mx = -INFINITY;
    for (int j = 0; j < 30; ++j) mx = fmaxf(mx, s[j]);
    float sum = 0.f;
    for (int j = 0; j < 30; ++j) { const float e = expf(s[j] - mx); w[j] = e; sum += e; }
    const float inv = 1.f / sum;
    for (int j = 0; j < 30; ++j) w[j] *= inv;
}

__global__ __launch_bounds__(256) void seq_kernel(
    const float* __restrict__ y,
    const float* __restrict__ gxg,      // 5730 x 768 (includes bx_g)
    const float* __restrict__ gxc,      // 5730 x 96  (includes bx_c)
    const float* __restrict__ pbox_b,   // 5730 x 36  (bfeat part + b_pbox)
    const float* __restrict__ logit_b,  // 5730       (bfeat part + b_out)
    const float* __restrict__ Whg,      // 256 x 768
    const float* __restrict__ bhg,      // 768
    const float* __restrict__ Whc,      // 32 x 96
    const float* __restrict__ bhc,      // 96
    const float* __restrict__ Wpbox,    // 544 x 36
    const float* __restrict__ Wout,     // 544
    float* __restrict__ h2buf,          // 2 x 30 x 256
    float* __restrict__ hc2buf,         // 2 x 30 x 32
    unsigned* __restrict__ bar,
    float* __restrict__ partials)       // 60
{
    const int r = blockIdx.x;
    const int tid = threadIdx.x;
    __shared__ float h[256], hn[256], h2l[256];
    __shared__ float hcs[32], hcn[32], hc2l[32];
    __shared__ float sc[32], sc2[32], attw[32], attw2[32], pbl[40];

    h[tid] = 0.f;
    if (tid < 32) hcs[tid] = 0.f;
    __syncthreads();

    const float invnorm[4] = {1.f/1920.f, 1.f/1200.f, 1.f/1920.f, 1.f/1200.f};
    float bacc = 0.f, oacc = 0.f;

    for (int t = 0; t < T_STEPS; ++t) {
        const int m = t * 30 + r;
        const bool act = (y[m * YS] != 0.f);
        const float actf = act ? 1.f : 0.f;
        const int buf = t & 1;

        // ---- h-GRU recurrent half ----
        {
            float gr = bhg[tid], gz = bhg[256 + tid], gn = bhg[512 + tid];
            #pragma unroll 4
            for (int k = 0; k < 256; ++k) {
                const float hk = h[k];
                gr = fmaf(hk, Whg[k * 768 + tid], gr);
                gz = fmaf(hk, Whg[k * 768 + 256 + tid], gz);
                gn = fmaf(hk, Whg[k * 768 + 512 + tid], gn);
            }
            const float xr = gxg[(size_t)m * 768 + tid];
            const float xz = gxg[(size_t)m * 768 + 256 + tid];
            const float xn = gxg[(size_t)m * 768 + 512 + tid];
            const float rg = sigmoid_(xr + gr);
            const float zg = sigmoid_(xz + gz);
            const float ng = tanhf(xn + rg * gn);
            const float hnv = (1.f - zg) * ng + zg * h[tid];
            hn[tid] = hnv;
            const float h2v = act ? hnv : h[tid];
            h2l[tid] = h2v;
            h2buf[buf * (30 * 256) + r * 256 + tid] = h2v;
        }
        // ---- hc-GRU recurrent half ----
        if (tid < 32) {
            float gr = bhc[tid], gz = bhc[32 + tid], gn = bhc[64 + tid];
            #pragma unroll
            for (int k = 0; k < 32; ++k) {
                const float hk = hcs[k];
                gr = fmaf(hk, Whc[k * 96 + tid], gr);
                gz = fmaf(hk, Whc[k * 96 + 32 + tid], gz);
                gn = fmaf(hk, Whc[k * 96 + 64 + tid], gn);
            }
            const float xr = gxc[m * 96 + tid];
            const float xz = gxc[m * 96 + 32 + tid];
            const float xn = gxc[m * 96 + 64 + tid];
            const float rg = sigmoid_(xr + gr);
            const float zg = sigmoid_(xz + gz);
            const float ng = tanhf(xn + rg * gn);
            const float hv = (1.f - zg) * ng + zg * hcs[tid];
            hcn[tid] = hv;
            const float h2v = act ? hv : hcs[tid];
            hc2l[tid] = h2v;
            hc2buf[buf * (30 * 32) + r * 32 + tid] = h2v;
        }
        __syncthreads();

        // ---- heads: pbox cols (36) + logit, only h_n/hc_n parts remain ----
        if (tid < 36) {
            float s = pbox_b[m * 36 + tid];
            for (int k = 0; k < 256; ++k) s = fmaf(hn[k], Wpbox[k * 36 + tid], s);
            #pragma unroll
            for (int k = 0; k < 32; ++k) s = fmaf(hcn[k], Wpbox[(512 + k) * 36 + tid], s);
            pbl[tid] = s;
        } else if (tid == 36) {
            float s = logit_b[m];
            for (int k = 0; k < 256; ++k) s = fmaf(hn[k], Wout[k], s);
            #pragma unroll
            for (int k = 0; k < 32; ++k) s = fmaf(hcn[k], Wout[512 + k], s);
            pbl[36] = s;
        }
        __syncthreads();

        // ---- losses (thread 0) ----
        if (tid == 0) {
            float sl = 0.f;
            for (int c = 0; c < 36; ++c) {
                const int s4 = c >> 2, cc = c & 3;
                const float fut = y[((t + 1 + s4) * 30 + r) * YS + 1 + cc] * invnorm[cc];
                const float d = pbl[c] - fut;
                const float ad = fabsf(d);
                sl += (ad < 1.f) ? 0.5f * d * d : (ad - 0.5f);
            }
            bacc += (sl * (1.f / 36.f)) * actf;
            const float l = pbl[36];
            const float tgt = y[m * YS + 5];
            const float bce = fmaxf(l, 0.f) - l * tgt + log1pf(expf(-fabsf(l)));
            oacc += 0.05f * bce * actf;
        }

        // ---- device-wide barrier (h2/hc2 published) ----
        __syncthreads();
        if (tid == 0) {
            __hip_atomic_fetch_add(bar, 1u, __ATOMIC_RELEASE, __HIP_MEMORY_SCOPE_AGENT);
            const unsigned tgtc = 30u * (unsigned)(t + 1);
            while (__hip_atomic_load(bar, __ATOMIC_ACQUIRE, __HIP_MEMORY_SCOPE_AGENT) < tgtc)
                __builtin_amdgcn_s_sleep(8);
        }
        __syncthreads();

        // ---- self-attention (h and hc) ----
        const float* hb  = h2buf  + buf * (30 * 256);
        const float* hcb = hc2buf + buf * (30 * 32);
        {
            const int jrow = tid >> 3, p = tid & 7;
            if (jrow < 30) {
                float s = 0.f;
                for (int k = p; k < 256; k += 8) s = fmaf(h2l[k], hb[jrow * 256 + k], s);
                s += __shfl_xor(s, 1); s += __shfl_xor(s, 2); s += __shfl_xor(s, 4);
                if (p == 0) {
                    const bool actj = (y[(t * 30 + jrow) * YS] != 0.f);
                    sc[jrow] = actj ? s * (1.f / 16.f) : -1e9f;
                }
            }
            if (tid < 30) {
                float s = 0.f;
                #pragma unroll
                for (int k = 0; k < 32; ++k) s = fmaf(hc2l[k], hcb[tid * 32 + k], s);
                const bool actj = (y[(t * 30 + tid) * YS] != 0.f);
                sc2[tid] = actj ? s * 0.17677669529663687f : -1e9f;  // 1/sqrt(32)
            }
        }
        __syncthreads();
        if (tid == 0)       softmax30(sc,  attw);
        else if (tid == 64) softmax30(sc2, attw2);
        __syncthreads();
        {
            float nh = 0.f;
            for (int j = 0; j < 30; ++j) nh = fmaf(attw[j], hb[j * 256 + tid], nh);
            h[tid] = act ? nh : h2l[tid];
            if (tid < 32) {
                float nc = 0.f;
                for (int j = 0; j < 30; ++j) nc = fmaf(attw2[j], hcb[j * 32 + tid], nc);
                hcs[tid] = act ? nc : hc2l[tid];
            }
        }
        __syncthreads();
    }

    if (tid == 0) { partials[r] = bacc; partials[30 + r] = oacc; }
}

__global__ void reduce_kernel(const float* __restrict__ partials, float* __restrict__ out) {
    if (threadIdx.x == 0) {
        float b = 0.f, o = 0.f;
        for (int i = 0; i < 30; ++i) { b += partials[i]; o += partials[30 + i]; }
        out[0] = o + b + 0.3f * b;
    }
}

// ---------------- launch ----------------
extern "C" void kernel_launch(void* const* d_in, const int* in_sizes, int n_in,
                              void* d_out, int out_size, void* d_ws, size_t ws_size,
                              hipStream_t stream) {
    (void)in_sizes; (void)n_in; (void)out_size; (void)ws_size;
    const float* y      = (const float*)d_in[1];
    const float* flow   = (const float*)d_in[3];
    const float* W_rgb  = (const float*)d_in[4];
    const float* b_rgb  = (const float*)d_in[5];
    const float* W_bb   = (const float*)d_in[6];
    const float* b_bb   = (const float*)d_in[7];
    const float* W_dd   = (const float*)d_in[8];
    const float* b_dd   = (const float*)d_in[9];
    const float* W_proj = (const float*)d_in[10];
    const float* b_proj = (const float*)d_in[11];
    const float* Wx_c   = (const float*)d_in[12];
    const float* Wh_c   = (const float*)d_in[13];
    const float* bx_c   = (const float*)d_in[14];
    const float* bh_c   = (const float*)d_in[15];
    const float* Wx_g   = (const float*)d_in[16];
    const float* Wh_g   = (const float*)d_in[17];
    const float* bx_g   = (const float*)d_in[18];
    const float* bh_g   = (const float*)d_in[19];
    const float* W_out  = (const float*)d_in[20];
    const float* b_out  = (const float*)d_in[21];
    const float* W_pbox = (const float*)d_in[22];
    const float* b_pbox = (const float*)d_in[23];
    float* out = (float*)d_out;

    char* ws = (char*)d_ws;
    unsigned* bar = (unsigned*)ws;
    float* base = (float*)(ws + 256);
    size_t off = 0;
    float* rgb    = base + off; off += (size_t)5921 * 256;
    float* gxg    = base + off; off += (size_t)5730 * 768;
    float* gxc    = base + off; off += (size_t)5730 * 96;
    float* pboxb  = base + off; off += (size_t)5730 * 36;
    float* logitb = base + off; off += 5730;
    float* h2b    = base + off; off += 2 * 30 * 256;
    float* hc2b   = base + off; off += 2 * 30 * 32;
    float* parts  = base + off; off += 64;

    hipMemsetAsync(d_ws, 0, 256, stream);  // barrier counter

    // rgb = relu(flow_f @ W_rgb + b_rgb): M=5921, K=4096, N=256
    gemm_tiled<false, true><<<dim3(4, 93), 256, 0, stream>>>(flow, W_rgb, b_rgb, rgb, 5921, 256, 4096);
    // gx_g = comb @ Wx_g + bx_g: M=5730, K=512, N=768 (comb gathered from rgb)
    gemm_tiled<true, false><<<dim3(12, 90), 256, 0, stream>>>(rgb, Wx_g, bx_g, gxg, 5730, 768, 512);
    // small per-(t,i) precompute
    precomp_kernel<<<5730, 256, 0, stream>>>(y, W_bb, b_bb, W_dd, b_dd, W_proj, b_proj,
                                             Wx_c, bx_c, W_pbox, b_pbox, W_out, b_out,
                                             gxc, pboxb, logitb);
    // sequential recurrence, 30 persistent blocks
    seq_kernel<<<30, 256, 0, stream>>>(y, gxg, gxc, pboxb, logitb, Wh_g, bh_g, Wh_c, bh_c,
                                       W_pbox, W_out, h2b, hc2b, bar, parts);
    reduce_kernel<<<1, 64, 0, stream>>>(parts, out);
}

// Round 2
// 5655.260 us; speedup vs baseline: 1.5541x; 1.5541x over previous
//
#include <hip/hip_runtime.h>
#include <hip/hip_bf16.h>
#include <math.h>

// ---------------- constants ----------------
#define T_STEPS 191      // 200 - 9
#define NB1 31
#define YS 13            // y feature stride

__device__ __forceinline__ float sigmoid_(float x) { return 1.f / (1.f + expf(-x)); }
__device__ __forceinline__ float bflo(unsigned u) { return __uint_as_float(u << 16); }
__device__ __forceinline__ float bfhi(unsigned u) { return __uint_as_float(u & 0xffff0000u); }

// ---------------- tiled fp32 GEMM: C = act(A @ B + bias) ----------------
template <bool GATHER, bool RELU>
__global__ __launch_bounds__(256) void gemm_tiled(
    const float* __restrict__ A, const float* __restrict__ B,
    const float* __restrict__ bias, float* __restrict__ C,
    int M, int N, int K)
{
    __shared__ float As[16][65];
    __shared__ float Bs[16][65];
    const int tid = threadIdx.x;
    const int tm = tid >> 4, tn = tid & 15;
    const int rowBase = blockIdx.y * 64;
    const int colBase = blockIdx.x * 64;
    float acc[4][4] = {};
    for (int kt = 0; kt < K; kt += 16) {
        #pragma unroll
        for (int l = 0; l < 4; ++l) {
            const int idx = tid + l * 256;
            const int kk = idx & 15, rr = idx >> 4;
            const int row = rowBase + rr;
            float v = 0.f;
            if (row < M) {
                if (GATHER) {
                    const int t = row / 30, i = row - t * 30;
                    const int k = kt + kk;
                    const int src = (k < 256) ? ((t * NB1 + i + 1) * 256 + k)
                                              : (t * NB1 * 256 + (k - 256));
                    v = A[src];
                } else {
                    v = A[(size_t)row * K + kt + kk];
                }
            }
            As[kk][rr] = v;
            const int nn = idx & 63, k2 = idx >> 6;
            Bs[k2][nn] = B[(size_t)(kt + k2) * N + colBase + nn];
        }
        __syncthreads();
        #pragma unroll
        for (int kk = 0; kk < 16; ++kk) {
            float a[4], b[4];
            #pragma unroll
            for (int i = 0; i < 4; ++i) a[i] = As[kk][tm * 4 + i];
            #pragma unroll
            for (int j = 0; j < 4; ++j) b[j] = Bs[kk][tn * 4 + j];
            #pragma unroll
            for (int i = 0; i < 4; ++i)
                #pragma unroll
                for (int j = 0; j < 4; ++j)
                    acc[i][j] = fmaf(a[i], b[j], acc[i][j]);
        }
        __syncthreads();
    }
    #pragma unroll
    for (int i = 0; i < 4; ++i) {
        const int row = rowBase + tm * 4 + i;
        if (row < M) {
            #pragma unroll
            for (int j = 0; j < 4; ++j) {
                const int col = colBase + tn * 4 + j;
                float v = acc[i][j] + bias[col];
                if (RELU) v = fmaxf(v, 0.f);
                C[(size_t)row * N + col] = v;
            }
        }
    }
}

// ---------------- prep: Whg fp32 -> packed bf16x2, layout [k2][768] ----------------
__global__ __launch_bounds__(256) void prep_w(const float* __restrict__ Whg, unsigned* __restrict__ wp)
{
    const int idx = blockIdx.x * 256 + threadIdx.x;   // 128*768 total
    if (idx >= 128 * 768) return;
    const int k2 = idx / 768, c = idx - k2 * 768;
    __hip_bfloat16 b0 = __float2bfloat16(Whg[(size_t)(2 * k2) * 768 + c]);
    __hip_bfloat16 b1 = __float2bfloat16(Whg[(size_t)(2 * k2 + 1) * 768 + c]);
    const unsigned lo = *reinterpret_cast<unsigned short*>(&b0);
    const unsigned hi = *reinterpret_cast<unsigned short*>(&b1);
    wp[idx] = lo | (hi << 16);
}

// combined biases: r/z gates get bx+bh (additive), n gate keeps bx only (ref: tanh(xn + r*hn))
__global__ void prep_bias(const float* __restrict__ bxg, const float* __restrict__ bhg,
                          const float* __restrict__ bxc, const float* __restrict__ bhc,
                          float* __restrict__ biasg, float* __restrict__ biasc)
{
    const int t = threadIdx.x;
    if (t < 768) biasg[t] = bxg[t] + (t < 512 ? bhg[t] : 0.f);
    if (t < 96)  biasc[t] = bxc[t] + (t < 64 ? bhc[t] : 0.f);
}

// ---------------- per-(t,obj) small precompute ----------------
__global__ __launch_bounds__(256) void precomp_kernel(
    const float* __restrict__ y,
    const float* __restrict__ Wbb, const float* __restrict__ bbb,
    const float* __restrict__ Wdd, const float* __restrict__ bdd,
    const float* __restrict__ Wproj, const float* __restrict__ bproj,
    const float* __restrict__ Wxc, const float* __restrict__ biasc,
    const float* __restrict__ Wpbox, const float* __restrict__ bpbox,
    const float* __restrict__ Wout, const float* __restrict__ bout,
    float* __restrict__ gxc, float* __restrict__ pbox_b, float* __restrict__ logit_b)
{
    const int m = blockIdx.x;
    const int tid = threadIdx.x;
    __shared__ float bf[256], df[256], xcs[32], yl[16];
    if (tid < YS) yl[tid] = y[m * YS + tid];
    __syncthreads();
    const float invnorm[4] = {1.f/1920.f, 1.f/1200.f, 1.f/1920.f, 1.f/1200.f};
    {
        float s = bbb[tid];
        s = fmaf(yl[1] * invnorm[0], Wbb[0 * 256 + tid], s);
        s = fmaf(yl[2] * invnorm[1], Wbb[1 * 256 + tid], s);
        s = fmaf(yl[3] * invnorm[2], Wbb[2 * 256 + tid], s);
        s = fmaf(yl[4] * invnorm[3], Wbb[3 * 256 + tid], s);
        s = fmaf(yl[6],              Wbb[4 * 256 + tid], s);
        bf[tid] = fmaxf(s, 0.f);
    }
    {
        float s = bdd[tid];
        #pragma unroll
        for (int k = 0; k < 6; ++k) s = fmaf(yl[7 + k], Wdd[k * 256 + tid], s);
        df[tid] = fmaxf(s, 0.f);
    }
    __syncthreads();
    // xc: 32 dots over 256, 8 lanes each (k-stride 8)
    {
        const int c = tid >> 3, p = tid & 7;
        float s = 0.f;
        for (int k = p; k < 256; k += 8) s = fmaf(df[k], Wproj[k * 32 + c], s);
        s += __shfl_xor(s, 1); s += __shfl_xor(s, 2); s += __shfl_xor(s, 4);
        if (p == 0) xcs[c] = s + bproj[c];
    }
    __syncthreads();
    if (tid < 96) {
        float s = biasc[tid];
        #pragma unroll
        for (int k = 0; k < 32; ++k) s = fmaf(xcs[k], Wxc[k * 96 + tid], s);
        gxc[m * 96 + tid] = s;
    }
    // pbox_b (36 dots) + logit_b (1 dot), 4 lanes each over bfeat k=256
    {
        const int d = tid >> 2, p = tid & 3;
        if (d < 37) {
            float s = 0.f;
            if (d < 36) {
                for (int k = p; k < 256; k += 4) s = fmaf(bf[k], Wpbox[(256 + k) * 36 + d], s);
            } else {
                for (int k = p; k < 256; k += 4) s = fmaf(bf[k], Wout[256 + k], s);
            }
            s += __shfl_xor(s, 1); s += __shfl_xor(s, 2);
            if (p == 0) {
                if (d < 36) pbox_b[m * 36 + d] = s + bpbox[d];
                else        logit_b[m] = s + bout[0];
            }
        }
    }
}

// ---------------- sequential recurrence: 30 persistent blocks x 768 threads ----------------
__device__ __forceinline__ void softmax30(const float* s, float* w) {
    float mx = -INFINITY;
    for (int j = 0; j < 30; ++j) mx = fmaxf(mx, s[j]);
    float sum = 0.f;
    for (int j = 0; j < 30; ++j) { const float e = expf(s[j] - mx); w[j] = e; sum += e; }
    const float inv = 1.f / sum;
    for (int j = 0; j < 30; ++j) w[j] *= inv;
}

__global__ __launch_bounds__(768) void seq_kernel(
    const float* __restrict__ y,
    const float* __restrict__ gxg,      // 5730 x 768 (r/z incl bx+bh, n incl bx)
    const float* __restrict__ gxc,      // 5730 x 96
    const float* __restrict__ pbox_b,   // 5730 x 36
    const float* __restrict__ logit_b,  // 5730
    const unsigned* __restrict__ wp,    // 128 x 768 packed bf16x2 of Whg
    const float* __restrict__ bhg,      // 768 (n-part used)
    const float* __restrict__ Whc,      // 32 x 96 fp32
    const float* __restrict__ bhc,      // 96 (n-part used)
    const float* __restrict__ Wpbox,    // 544 x 36
    const float* __restrict__ Wout,     // 544
    float* __restrict__ h2buf,          // 2 x 30 x 256
    float* __restrict__ hc2buf,         // 2 x 30 x 32
    unsigned* __restrict__ bar,
    float* __restrict__ partials)
{
    const int r = blockIdx.x;
    const int tid = threadIdx.x;
    __shared__ __align__(16) float h[256];
    __shared__ float gat[768];
    __shared__ float hn[256], h2l[256];
    __shared__ float hcs[32], hcg[96], hcn[32], hc2l[32];
    __shared__ float whc[32 * 96];
    __shared__ float sc[32], sc2[32], attw[32], attw2[32], pbl[40];

    for (int i = tid; i < 32 * 96; i += 768) whc[i] = Whc[i];
    if (tid < 256) h[tid] = 0.f;
    if (tid < 32) hcs[tid] = 0.f;
    __syncthreads();

    float bacc = 0.f, oacc = 0.f;
    const float invnorm[4] = {1.f/1920.f, 1.f/1200.f, 1.f/1920.f, 1.f/1200.f};

    for (int t = 0; t < T_STEPS; ++t) {
        const int m = t * 30 + r;
        const bool act = (y[m * YS] != 0.f);
        const float actf = act ? 1.f : 0.f;
        const int buf = t & 1;

        // ---- stage 1: h-gate dots (one gate-col per thread), bf16 weights ----
        {
            const unsigned* wc = wp + tid;
            const float4* h4 = (const float4*)h;
            float acc = 0.f;
            #pragma unroll 8
            for (int k2 = 0; k2 < 128; k2 += 2) {
                const float4 hv = h4[k2 >> 1];
                const unsigned w0 = wc[(size_t)k2 * 768];
                const unsigned w1 = wc[(size_t)(k2 + 1) * 768];
                acc = fmaf(hv.x, bflo(w0), acc);
                acc = fmaf(hv.y, bfhi(w0), acc);
                acc = fmaf(hv.z, bflo(w1), acc);
                acc = fmaf(hv.w, bfhi(w1), acc);
            }
            // r/z cols: add x-side (incl both biases); n cols: add bh_n only
            gat[tid] = acc + (tid < 512 ? gxg[(size_t)m * 768 + tid] : bhg[tid]);
        }
        if (tid < 96) {  // hc-gate dots (k=32, LDS weights)
            float a = (tid < 64) ? gxc[m * 96 + tid] : bhc[tid];
            #pragma unroll
            for (int k = 0; k < 32; ++k) a = fmaf(hcs[k], whc[k * 96 + tid], a);
            hcg[tid] = a;
        }
        __syncthreads();

        // ---- stage 2: GRU combine + publish h2/hc2 ----
        if (tid < 256) {
            const float rg = sigmoid_(gat[tid]);
            const float zg = sigmoid_(gat[256 + tid]);
            const float xn = gxg[(size_t)m * 768 + 512 + tid];
            const float ng = tanhf(xn + rg * gat[512 + tid]);
            const float hv = h[tid];
            const float hnv = (1.f - zg) * ng + zg * hv;
            hn[tid] = hnv;
            const float h2v = act ? hnv : hv;
            h2l[tid] = h2v;
            h2buf[buf * (30 * 256) + r * 256 + tid] = h2v;
        } else if (tid < 288) {
            const int j = tid - 256;
            const float rg = sigmoid_(hcg[j]);
            const float zg = sigmoid_(hcg[32 + j]);
            const float xn = gxc[m * 96 + 64 + j];
            const float ng = tanhf(xn + rg * hcg[64 + j]);
            const float hv = hcs[j];
            const float hvn = (1.f - zg) * ng + zg * hv;
            hcn[j] = hvn;
            const float h2v = act ? hvn : hv;
            hc2l[j] = h2v;
            hc2buf[buf * (30 * 32) + r * 32 + j] = h2v;
        }
        __syncthreads();

        // ---- stage 3: heads (37 dots x 16 lanes, k-strided) ----
        if (tid < 592) {
            const int d = tid >> 4, p = tid & 15;
            float s = 0.f;
            if (d < 36) {
                for (int k = p; k < 256; k += 16) s = fmaf(hn[k], Wpbox[k * 36 + d], s);
                for (int k = p; k < 32; k += 16)  s = fmaf(hcn[k], Wpbox[(512 + k) * 36 + d], s);
            } else {
                for (int k = p; k < 256; k += 16) s = fmaf(hn[k], Wout[k], s);
                for (int k = p; k < 32; k += 16)  s = fmaf(hcn[k], Wout[512 + k], s);
            }
            s += __shfl_xor(s, 1); s += __shfl_xor(s, 2); s += __shfl_xor(s, 4); s += __shfl_xor(s, 8);
            if (p == 0) pbl[d] = s + (d < 36 ? pbox_b[m * 36 + d] : logit_b[m]);
        }
        __syncthreads();

        // ---- stage 4: losses ----
        if (tid == 0) {
            float sl = 0.f;
            #pragma unroll 4
            for (int c = 0; c < 36; ++c) {
                const int s4 = c >> 2, cc = c & 3;
                const float fut = y[((t + 1 + s4) * 30 + r) * YS + 1 + cc] * invnorm[cc];
                const float d = pbl[c] - fut;
                const float ad = fabsf(d);
                sl += (ad < 1.f) ? 0.5f * d * d : (ad - 0.5f);
            }
            bacc += (sl * (1.f / 36.f)) * actf;
            const float l = pbl[36];
            const float tgt = y[m * YS + 5];
            const float bce = fmaxf(l, 0.f) - l * tgt + log1pf(expf(-fabsf(l)));
            oacc += 0.05f * bce * actf;
        }
        __syncthreads();

        // ---- stage 5: device-wide barrier (h2/hc2 published) ----
        if (tid == 0) {
            __hip_atomic_fetch_add(bar, 1u, __ATOMIC_RELEASE, __HIP_MEMORY_SCOPE_AGENT);
            const unsigned tgtc = 30u * (unsigned)(t + 1);
            while (__hip_atomic_load(bar, __ATOMIC_ACQUIRE, __HIP_MEMORY_SCOPE_AGENT) < tgtc)
                __builtin_amdgcn_s_sleep(2);
        }
        __syncthreads();

        // ---- stage 6: self-attention ----
        const float* hb  = h2buf  + buf * (30 * 256);
        const float* hcb = hc2buf + buf * (30 * 32);
        if (tid < 480) {
            const int j = tid >> 4, p = tid & 15;
            float s = 0.f;
            for (int k = p; k < 256; k += 16) s = fmaf(h2l[k], hb[j * 256 + k], s);
            s += __shfl_xor(s, 1); s += __shfl_xor(s, 2); s += __shfl_xor(s, 4); s += __shfl_xor(s, 8);
            if (p == 0) {
                const bool actj = (y[(t * 30 + j) * YS] != 0.f);
                sc[j] = actj ? s * (1.f / 16.f) : -1e9f;
            }
        } else if (tid < 510) {
            const int j = tid - 480;
            float s = 0.f;
            #pragma unroll
            for (int k = 0; k < 32; ++k) s = fmaf(hc2l[k], hcb[j * 32 + k], s);
            const bool actj = (y[(t * 30 + j) * YS] != 0.f);
            sc2[j] = actj ? s * 0.17677669529663687f : -1e9f;
        }
        __syncthreads();
        if (tid == 0)       softmax30(sc,  attw);
        else if (tid == 64) softmax30(sc2, attw2);
        __syncthreads();
        if (tid < 256) {
            float nh = 0.f;
            #pragma unroll 6
            for (int j = 0; j < 30; ++j) nh = fmaf(attw[j], hb[j * 256 + tid], nh);
            h[tid] = act ? nh : h2l[tid];
        } else if (tid < 288) {
            const int j2 = tid - 256;
            float nc = 0.f;
            #pragma unroll
            for (int j = 0; j < 30; ++j) nc = fmaf(attw2[j], hcb[j * 32 + j2], nc);
            hcs[j2] = act ? nc : hc2l[j2];
        }
        __syncthreads();
    }

    if (tid == 0) { partials[r] = bacc; partials[30 + r] = oacc; }
}

__global__ void reduce_kernel(const float* __restrict__ partials, float* __restrict__ out) {
    if (threadIdx.x == 0) {
        float b = 0.f, o = 0.f;
        for (int i = 0; i < 30; ++i) { b += partials[i]; o += partials[30 + i]; }
        out[0] = o + b + 0.3f * b;
    }
}

// ---------------- launch ----------------
extern "C" void kernel_launch(void* const* d_in, const int* in_sizes, int n_in,
                              void* d_out, int out_size, void* d_ws, size_t ws_size,
                              hipStream_t stream) {
    (void)in_sizes; (void)n_in; (void)out_size; (void)ws_size;
    const float* y      = (const float*)d_in[1];
    const float* flow   = (const float*)d_in[3];
    const float* W_rgb  = (const float*)d_in[4];
    const float* b_rgb  = (const float*)d_in[5];
    const float* W_bb   = (const float*)d_in[6];
    const float* b_bb   = (const float*)d_in[7];
    const float* W_dd   = (const float*)d_in[8];
    const float* b_dd   = (const float*)d_in[9];
    const float* W_proj = (const float*)d_in[10];
    const float* b_proj = (const float*)d_in[11];
    const float* Wx_c   = (const float*)d_in[12];
    const float* Wh_c   = (const float*)d_in[13];
    const float* bx_c   = (const float*)d_in[14];
    const float* bh_c   = (const float*)d_in[15];
    const float* Wx_g   = (const float*)d_in[16];
    const float* Wh_g   = (const float*)d_in[17];
    const float* bx_g   = (const float*)d_in[18];
    const float* bh_g   = (const float*)d_in[19];
    const float* W_out  = (const float*)d_in[20];
    const float* b_out  = (const float*)d_in[21];
    const float* W_pbox = (const float*)d_in[22];
    const float* b_pbox = (const float*)d_in[23];
    float* out = (float*)d_out;

    char* ws = (char*)d_ws;
    unsigned* bar = (unsigned*)ws;
    float* base = (float*)(ws + 256);
    size_t off = 0;
    float* rgb    = base + off; off += (size_t)5921 * 256;
    float* gxg    = base + off; off += (size_t)5730 * 768;
    float* gxc    = base + off; off += (size_t)5730 * 96;
    float* pboxb  = base + off; off += (size_t)5730 * 36;
    float* logitb = base + off; off += 5730;
    float* h2b    = base + off; off += 2 * 30 * 256;
    float* hc2b   = base + off; off += 2 * 30 * 32;
    float* parts  = base + off; off += 64;
    unsigned* wp  = (unsigned*)(base + off); off += 128 * 768;
    float* biasg  = base + off; off += 768;
    float* biasc  = base + off; off += 96;

    hipMemsetAsync(d_ws, 0, 256, stream);  // barrier counter

    prep_w<<<(128 * 768 + 255) / 256, 256, 0, stream>>>(Wh_g, wp);
    prep_bias<<<1, 768, 0, stream>>>(bx_g, bh_g, bx_c, bh_c, biasg, biasc);

    // rgb = relu(flow_f @ W_rgb + b_rgb): M=5921, K=4096, N=256
    gemm_tiled<false, true><<<dim3(4, 93), 256, 0, stream>>>(flow, W_rgb, b_rgb, rgb, 5921, 256, 4096);
    // gx_g = comb @ Wx_g + biasg: M=5730, K=512, N=768
    gemm_tiled<true, false><<<dim3(12, 90), 256, 0, stream>>>(rgb, Wx_g, biasg, gxg, 5730, 768, 512);
    precomp_kernel<<<5730, 256, 0, stream>>>(y, W_bb, b_bb, W_dd, b_dd, W_proj, b_proj,
                                             Wx_c, biasc, W_pbox, b_pbox, W_out, b_out,
                                             gxc, pboxb, logitb);
    seq_kernel<<<30, 768, 0, stream>>>(y, gxg, gxc, pboxb, logitb, wp, bh_g, Wh_c, bh_c,
                                       W_pbox, W_out, h2b, hc2b, bar, parts);
    reduce_kernel<<<1, 64, 0, stream>>>(parts, out);
}

// Round 4
// 5085.954 us; speedup vs baseline: 1.7281x; 1.1119x over previous
//
#include <hip/hip_runtime.h>
#include <hip/hip_bf16.h>
#include <math.h>
#include <stdint.h>

// ---------------- constants ----------------
#define T_STEPS 191      // 200 - 9
#define NB1 31
#define YS 13            // y feature stride

__device__ __forceinline__ float sigmoid_(float x) { return 1.f / (1.f + expf(-x)); }
__device__ __forceinline__ float bflo(unsigned u) { return __uint_as_float(u << 16); }
__device__ __forceinline__ float bfhi(unsigned u) { return __uint_as_float(u & 0xffff0000u); }

// ---- cross-XCD coherent ops: bypass non-coherent per-XCD L2 (sc0 sc1 -> MALL) ----
// NOTE: inline-asm 'v' INPUTS must be <=64-bit (128-bit vector inputs unsupported);
// 128-bit "=v" OUTPUTS are fine.
__device__ __forceinline__ void store_dw_mall(float* p, float v) {
    asm volatile("global_store_dword %0, %1, off sc0 sc1"
                 :: "v"((uintptr_t)p), "v"(v) : "memory");
}
__device__ __forceinline__ void atomic_inc_mall(unsigned* p) {
    asm volatile("global_atomic_add %0, %1, off sc1"
                 :: "v"((uintptr_t)p), "v"(1u) : "memory");
}
__device__ __forceinline__ unsigned load_u32_mall(const unsigned* p) {
    unsigned v;
    asm volatile("global_load_dword %0, %1, off sc0 sc1\n\ts_waitcnt vmcnt(0)"
                 : "=v"(v) : "v"((uintptr_t)p) : "memory");
    return v;
}

// ---------------- tiled fp32 GEMM: C = act(A @ B + bias) ----------------
template <bool GATHER, bool RELU>
__global__ __launch_bounds__(256) void gemm_tiled(
    const float* __restrict__ A, const float* __restrict__ B,
    const float* __restrict__ bias, float* __restrict__ C,
    int M, int N, int K)
{
    __shared__ float As[16][65];
    __shared__ float Bs[16][65];
    const int tid = threadIdx.x;
    const int tm = tid >> 4, tn = tid & 15;
    const int rowBase = blockIdx.y * 64;
    const int colBase = blockIdx.x * 64;
    float acc[4][4] = {};
    for (int kt = 0; kt < K; kt += 16) {
        #pragma unroll
        for (int l = 0; l < 4; ++l) {
            const int idx = tid + l * 256;
            const int kk = idx & 15, rr = idx >> 4;
            const int row = rowBase + rr;
            float v = 0.f;
            if (row < M) {
                if (GATHER) {
                    const int t = row / 30, i = row - t * 30;
                    const int k = kt + kk;
                    const int src = (k < 256) ? ((t * NB1 + i + 1) * 256 + k)
                                              : (t * NB1 * 256 + (k - 256));
                    v = A[src];
                } else {
                    v = A[(size_t)row * K + kt + kk];
                }
            }
            As[kk][rr] = v;
            const int nn = idx & 63, k2 = idx >> 6;
            Bs[k2][nn] = B[(size_t)(kt + k2) * N + colBase + nn];
        }
        __syncthreads();
        #pragma unroll
        for (int kk = 0; kk < 16; ++kk) {
            float a[4], b[4];
            #pragma unroll
            for (int i = 0; i < 4; ++i) a[i] = As[kk][tm * 4 + i];
            #pragma unroll
            for (int j = 0; j < 4; ++j) b[j] = Bs[kk][tn * 4 + j];
            #pragma unroll
            for (int i = 0; i < 4; ++i)
                #pragma unroll
                for (int j = 0; j < 4; ++j)
                    acc[i][j] = fmaf(a[i], b[j], acc[i][j]);
        }
        __syncthreads();
    }
    #pragma unroll
    for (int i = 0; i < 4; ++i) {
        const int row = rowBase + tm * 4 + i;
        if (row < M) {
            #pragma unroll
            for (int j = 0; j < 4; ++j) {
                const int col = colBase + tn * 4 + j;
                float v = acc[i][j] + bias[col];
                if (RELU) v = fmaxf(v, 0.f);
                C[(size_t)row * N + col] = v;
            }
        }
    }
}

// ---------------- prep: Whg fp32 -> packed bf16x2, layout [k2][768] ----------------
__global__ __launch_bounds__(256) void prep_w(const float* __restrict__ Whg, unsigned* __restrict__ wp)
{
    const int idx = blockIdx.x * 256 + threadIdx.x;   // 128*768 total
    if (idx >= 128 * 768) return;
    const int k2 = idx / 768, c = idx - k2 * 768;
    __hip_bfloat16 b0 = __float2bfloat16(Whg[(size_t)(2 * k2) * 768 + c]);
    __hip_bfloat16 b1 = __float2bfloat16(Whg[(size_t)(2 * k2 + 1) * 768 + c]);
    const unsigned lo = *reinterpret_cast<unsigned short*>(&b0);
    const unsigned hi = *reinterpret_cast<unsigned short*>(&b1);
    wp[idx] = lo | (hi << 16);
}

// combined biases: r/z gates get bx+bh (additive), n gate keeps bx only
__global__ void prep_bias(const float* __restrict__ bxg, const float* __restrict__ bhg,
                          const float* __restrict__ bxc, const float* __restrict__ bhc,
                          float* __restrict__ biasg, float* __restrict__ biasc)
{
    const int t = threadIdx.x;
    if (t < 768) biasg[t] = bxg[t] + (t < 512 ? bhg[t] : 0.f);
    if (t < 96)  biasc[t] = bxc[t] + (t < 64 ? bhc[t] : 0.f);
}

// ---------------- per-(t,obj) small precompute ----------------
__global__ __launch_bounds__(256) void precomp_kernel(
    const float* __restrict__ y,
    const float* __restrict__ Wbb, const float* __restrict__ bbb,
    const float* __restrict__ Wdd, const float* __restrict__ bdd,
    const float* __restrict__ Wproj, const float* __restrict__ bproj,
    const float* __restrict__ Wxc, const float* __restrict__ biasc,
    const float* __restrict__ Wpbox, const float* __restrict__ bpbox,
    const float* __restrict__ Wout, const float* __restrict__ bout,
    float* __restrict__ gxc, float* __restrict__ pbox_b, float* __restrict__ logit_b)
{
    const int m = blockIdx.x;
    const int tid = threadIdx.x;
    __shared__ float bf[256], df[256], xcs[32], yl[16];
    if (tid < YS) yl[tid] = y[m * YS + tid];
    __syncthreads();
    const float invnorm[4] = {1.f/1920.f, 1.f/1200.f, 1.f/1920.f, 1.f/1200.f};
    {
        float s = bbb[tid];
        s = fmaf(yl[1] * invnorm[0], Wbb[0 * 256 + tid], s);
        s = fmaf(yl[2] * invnorm[1], Wbb[1 * 256 + tid], s);
        s = fmaf(yl[3] * invnorm[2], Wbb[2 * 256 + tid], s);
        s = fmaf(yl[4] * invnorm[3], Wbb[3 * 256 + tid], s);
        s = fmaf(yl[6],              Wbb[4 * 256 + tid], s);
        bf[tid] = fmaxf(s, 0.f);
    }
    {
        float s = bdd[tid];
        #pragma unroll
        for (int k = 0; k < 6; ++k) s = fmaf(yl[7 + k], Wdd[k * 256 + tid], s);
        df[tid] = fmaxf(s, 0.f);
    }
    __syncthreads();
    {
        const int c = tid >> 3, p = tid & 7;
        float s = 0.f;
        for (int k = p; k < 256; k += 8) s = fmaf(df[k], Wproj[k * 32 + c], s);
        s += __shfl_xor(s, 1); s += __shfl_xor(s, 2); s += __shfl_xor(s, 4);
        if (p == 0) xcs[c] = s + bproj[c];
    }
    __syncthreads();
    if (tid < 96) {
        float s = biasc[tid];
        #pragma unroll
        for (int k = 0; k < 32; ++k) s = fmaf(xcs[k], Wxc[k * 96 + tid], s);
        gxc[m * 96 + tid] = s;
    }
    {
        const int d = tid >> 2, p = tid & 3;
        if (d < 37) {
            float s = 0.f;
            if (d < 36) {
                for (int k = p; k < 256; k += 4) s = fmaf(bf[k], Wpbox[(256 + k) * 36 + d], s);
            } else {
                for (int k = p; k < 256; k += 4) s = fmaf(bf[k], Wout[256 + k], s);
            }
            s += __shfl_xor(s, 1); s += __shfl_xor(s, 2);
            if (p == 0) {
                if (d < 36) pbox_b[m * 36 + d] = s + bpbox[d];
                else        logit_b[m] = s + bout[0];
            }
        }
    }
}

// ---------------- sequential recurrence: 30 persistent blocks x 768 threads ----------------
__device__ __forceinline__ void softmax30(const float* s, float* w) {
    float mx = -INFINITY;
    for (int j = 0; j < 30; ++j) mx = fmaxf(mx, s[j]);
    float sum = 0.f;
    for (int j = 0; j < 30; ++j) { const float e = expf(s[j] - mx); w[j] = e; sum += e; }
    const float inv = 1.f / sum;
    for (int j = 0; j < 30; ++j) w[j] *= inv;
}

#define PH 260   // h2s LDS pitch (floats)
#define PC 36    // hc2s LDS pitch (floats)

__global__ __launch_bounds__(768) void seq_kernel(
    const float* __restrict__ y,
    const float* __restrict__ gxg,      // 5730 x 768
    const float* __restrict__ gxc,      // 5730 x 96
    const float* __restrict__ pbox_b,   // 5730 x 36
    const float* __restrict__ logit_b,  // 5730
    const unsigned* __restrict__ wp,    // 128 x 768 packed bf16x2 of Whg
    const float* __restrict__ bhg,      // 768 (n-part used)
    const float* __restrict__ Whc,      // 32 x 96 fp32
    const float* __restrict__ bhc,      // 96 (n-part used)
    const float* __restrict__ Wpbox,    // 544 x 36
    const float* __restrict__ Wout,     // 544
    float* __restrict__ h2buf,          // 2 x 30 x 256
    float* __restrict__ hc2buf,         // 2 x 30 x 32
    unsigned* __restrict__ bar,
    float* __restrict__ partials)
{
    const int r = blockIdx.x;
    const int tid = threadIdx.x;
    __shared__ __align__(16) float h[256];
    __shared__ float gat[768];
    __shared__ float hn[256];
    __shared__ __align__(16) float h2l[256];
    __shared__ float hcs[32], hcg[96], hcn[32];
    __shared__ __align__(16) float hc2l[32];
    __shared__ float whc[32 * 96];
    __shared__ float sc[32], sc2[32], attw[32], attw2[32], pbl[40];
    __shared__ __align__(16) float h2s[30 * PH];
    __shared__ __align__(16) float hc2s[30 * PC];

    for (int i = tid; i < 32 * 96; i += 768) whc[i] = Whc[i];
    if (tid < 256) h[tid] = 0.f;
    if (tid < 32) hcs[tid] = 0.f;
    __syncthreads();

    float bacc = 0.f, oacc = 0.f;

    for (int t = 0; t < T_STEPS; ++t) {
        const int m = t * 30 + r;
        const bool act = (y[m * YS] != 0.f);
        const float actf = act ? 1.f : 0.f;
        const int buf = t & 1;
        float* hb  = h2buf  + buf * (30 * 256);
        float* hcb = hc2buf + buf * (30 * 32);

        // ---- stage 1: h-gate dots (one gate-col per thread), bf16 weights (L2-warm) ----
        {
            const unsigned* wc = wp + tid;
            const float4* h4 = (const float4*)h;
            float acc = 0.f;
            #pragma unroll 8
            for (int k2 = 0; k2 < 128; k2 += 2) {
                const float4 hv = h4[k2 >> 1];
                const unsigned w0 = wc[(size_t)k2 * 768];
                const unsigned w1 = wc[(size_t)(k2 + 1) * 768];
                acc = fmaf(hv.x, bflo(w0), acc);
                acc = fmaf(hv.y, bfhi(w0), acc);
                acc = fmaf(hv.z, bflo(w1), acc);
                acc = fmaf(hv.w, bfhi(w1), acc);
            }
            gat[tid] = acc + (tid < 512 ? gxg[(size_t)m * 768 + tid] : bhg[tid]);
        }
        if (tid < 96) {  // hc-gate dots (k=32, LDS weights)
            float a = (tid < 64) ? gxc[m * 96 + tid] : bhc[tid];
            #pragma unroll
            for (int k = 0; k < 32; ++k) a = fmaf(hcs[k], whc[k * 96 + tid], a);
            hcg[tid] = a;
        }
        __syncthreads();

        // ---- stage 2: GRU combine -> hn, h2 (LDS) + publish via MALL dword stores ----
        if (tid < 256) {
            const float rg = sigmoid_(gat[tid]);
            const float zg = sigmoid_(gat[256 + tid]);
            const float xn = gxg[(size_t)m * 768 + 512 + tid];
            const float ng = tanhf(xn + rg * gat[512 + tid]);
            const float hv = h[tid];
            const float hnv = (1.f - zg) * ng + zg * hv;
            hn[tid] = hnv;
            const float h2v = act ? hnv : hv;
            h2l[tid] = h2v;
            store_dw_mall(hb + r * 256 + tid, h2v);
        } else if (tid < 288) {
            const int j = tid - 256;
            const float rg = sigmoid_(hcg[j]);
            const float zg = sigmoid_(hcg[32 + j]);
            const float xn = gxc[m * 96 + 64 + j];
            const float ng = tanhf(xn + rg * hcg[64 + j]);
            const float hv = hcs[j];
            const float hvn = (1.f - zg) * ng + zg * hv;
            hcn[j] = hvn;
            const float h2v = act ? hvn : hv;
            hc2l[j] = h2v;
            store_dw_mall(hcb + r * 32 + j, h2v);
        }
        if (tid < 320) asm volatile("s_waitcnt vmcnt(0)" ::: "memory");  // waves 0-4 drain stores
        __syncthreads();

        // ---- stage 3: heads (37 dots x 16 lanes) ----
        if (tid < 592) {
            const int d = tid >> 4, p = tid & 15;
            float s = 0.f;
            if (d < 36) {
                for (int k = p; k < 256; k += 16) s = fmaf(hn[k], Wpbox[k * 36 + d], s);
                for (int k = p; k < 32; k += 16)  s = fmaf(hcn[k], Wpbox[(512 + k) * 36 + d], s);
            } else {
                for (int k = p; k < 256; k += 16) s = fmaf(hn[k], Wout[k], s);
                for (int k = p; k < 32; k += 16)  s = fmaf(hcn[k], Wout[512 + k], s);
            }
            s += __shfl_xor(s, 1); s += __shfl_xor(s, 2); s += __shfl_xor(s, 4); s += __shfl_xor(s, 8);
            if (p == 0) pbl[d] = s + (d < 36 ? pbox_b[m * 36 + d] : logit_b[m]);
        }
        __syncthreads();   // pbl ready; all publication stores drained

        // ---- stage 4: losses (wave 0 parallel) + barrier entry (lane 0) ----
        if (tid < 64) {
            float term = 0.f;
            if (tid < 36) {
                const int s4 = tid >> 2, cc = tid & 3;
                const float fnorm = (cc & 1) ? (1.f / 1200.f) : (1.f / 1920.f);
                const float fut = y[((t + 1 + s4) * 30 + r) * YS + 1 + cc] * fnorm;
                const float d = pbl[tid] - fut;
                const float ad = fabsf(d);
                term = (ad < 1.f) ? 0.5f * d * d : (ad - 0.5f);
            }
            #pragma unroll
            for (int o = 1; o < 64; o <<= 1) term += __shfl_xor(term, o);
            if (tid == 0) {
                bacc += (term * (1.f / 36.f)) * actf;
                const float l = pbl[36];
                const float tgt = y[m * YS + 5];
                const float bce = fmaxf(l, 0.f) - l * tgt + log1pf(expf(-fabsf(l)));
                oacc += 0.05f * bce * actf;
                // barrier: relaxed MALL atomic + MALL spin (no cache-wide fences)
                atomic_inc_mall(bar);
                const unsigned tgtc = 30u * (unsigned)(t + 1);
                unsigned cur;
                do {
                    asm volatile("s_sleep 1" :::);
                    cur = load_u32_mall(bar);
                } while (cur < tgtc);
            }
        }
        __syncthreads();

        // ---- stage 5: cooperative MALL load of h2buf/hc2buf -> LDS ----
        {
            // 1920 f4 for h2 (30x256), 240 f4 for hc2 (30x32) => 2160 items
            const int it0 = tid, it1 = tid + 768, it2 = tid + 1536;
            const float* s0; const float* s1; const float* s2;
            float* d0; float* d1; float* d2;
            {
                const int i = it0;  // always < 1920
                s0 = hb + ((i >> 6) * 256 + (i & 63) * 4);
                d0 = &h2s[(i >> 6) * PH + (i & 63) * 4];
            }
            {
                const int i = it1;
                if (i < 1920) { s1 = hb + ((i >> 6) * 256 + (i & 63) * 4); d1 = &h2s[(i >> 6) * PH + (i & 63) * 4]; }
                else { const int i2 = i - 1920; s1 = hcb + ((i2 >> 3) * 32 + (i2 & 7) * 4); d1 = &hc2s[(i2 >> 3) * PC + (i2 & 7) * 4]; }
            }
            const bool has2 = (it2 < 2160);
            if (has2) {
                const int i = it2;
                if (i < 1920) { s2 = hb + ((i >> 6) * 256 + (i & 63) * 4); d2 = &h2s[(i >> 6) * PH + (i & 63) * 4]; }
                else { const int i2 = i - 1920; s2 = hcb + ((i2 >> 3) * 32 + (i2 & 7) * 4); d2 = &hc2s[(i2 >> 3) * PC + (i2 & 7) * 4]; }
            } else { s2 = s0; d2 = d0; }
            float4 v0, v1, v2;
            asm volatile("global_load_dwordx4 %0, %1, off sc0 sc1" : "=v"(v0) : "v"((uintptr_t)s0) : "memory");
            asm volatile("global_load_dwordx4 %0, %1, off sc0 sc1" : "=v"(v1) : "v"((uintptr_t)s1) : "memory");
            asm volatile("global_load_dwordx4 %0, %1, off sc0 sc1" : "=v"(v2) : "v"((uintptr_t)s2) : "memory");
            asm volatile("s_waitcnt vmcnt(0)" ::: "memory");
            *(float4*)d0 = v0;
            *(float4*)d1 = v1;
            if (has2) *(float4*)d2 = v2;
        }
        __syncthreads();

        // ---- stage 6: self-attention (reads LDS copies) ----
        if (tid < 480) {
            const int j = tid >> 4, p = tid & 15;
            float s = 0.f;
            for (int k = p; k < 256; k += 16) s = fmaf(h2l[k], h2s[j * PH + k], s);
            s += __shfl_xor(s, 1); s += __shfl_xor(s, 2); s += __shfl_xor(s, 4); s += __shfl_xor(s, 8);
            if (p == 0) {
                const bool actj = (y[(t * 30 + j) * YS] != 0.f);
                sc[j] = actj ? s * (1.f / 16.f) : -1e9f;
            }
        } else if (tid < 510) {
            const int j = tid - 480;
            float s = 0.f;
            #pragma unroll
            for (int k = 0; k < 32; ++k) s = fmaf(hc2l[k], hc2s[j * PC + k], s);
            const bool actj = (y[(t * 30 + j) * YS] != 0.f);
            sc2[j] = actj ? s * 0.17677669529663687f : -1e9f;
        }
        __syncthreads();
        if (tid == 0)       softmax30(sc,  attw);
        else if (tid == 64) softmax30(sc2, attw2);
        __syncthreads();
        if (tid < 256) {
            float nh = 0.f;
            #pragma unroll 6
            for (int j = 0; j < 30; ++j) nh = fmaf(attw[j], h2s[j * PH + tid], nh);
            h[tid] = act ? nh : h2l[tid];
        } else if (tid < 288) {
            const int j2 = tid - 256;
            float nc = 0.f;
            #pragma unroll
            for (int j = 0; j < 30; ++j) nc = fmaf(attw2[j], hc2s[j * PC + j2], nc);
            hcs[j2] = act ? nc : hc2l[j2];
        }
        __syncthreads();
    }

    if (tid == 0) { partials[r] = bacc; partials[30 + r] = oacc; }
}

__global__ void reduce_kernel(const float* __restrict__ partials, float* __restrict__ out) {
    if (threadIdx.x == 0) {
        float b = 0.f, o = 0.f;
        for (int i = 0; i < 30; ++i) { b += partials[i]; o += partials[30 + i]; }
        out[0] = o + b + 0.3f * b;
    }
}

// ---------------- launch ----------------
extern "C" void kernel_launch(void* const* d_in, const int* in_sizes, int n_in,
                              void* d_out, int out_size, void* d_ws, size_t ws_size,
                              hipStream_t stream) {
    (void)in_sizes; (void)n_in; (void)out_size; (void)ws_size;
    const float* y      = (const float*)d_in[1];
    const float* flow   = (const float*)d_in[3];
    const float* W_rgb  = (const float*)d_in[4];
    const float* b_rgb  = (const float*)d_in[5];
    const float* W_bb   = (const float*)d_in[6];
    const float* b_bb   = (const float*)d_in[7];
    const float* W_dd   = (const float*)d_in[8];
    const float* b_dd   = (const float*)d_in[9];
    const float* W_proj = (const float*)d_in[10];
    const float* b_proj = (const float*)d_in[11];
    const float* Wx_c   = (const float*)d_in[12];
    const float* Wh_c   = (const float*)d_in[13];
    const float* bx_c   = (const float*)d_in[14];
    const float* bh_c   = (const float*)d_in[15];
    const float* Wx_g   = (const float*)d_in[16];
    const float* Wh_g   = (const float*)d_in[17];
    const float* bx_g   = (const float*)d_in[18];
    const float* bh_g   = (const float*)d_in[19];
    const float* W_out  = (const float*)d_in[20];
    const float* b_out  = (const float*)d_in[21];
    const float* W_pbox = (const float*)d_in[22];
    const float* b_pbox = (const float*)d_in[23];
    float* out = (float*)d_out;

    char* ws = (char*)d_ws;
    unsigned* bar = (unsigned*)ws;
    float* base = (float*)(ws + 256);
    size_t off = 0;
    float* rgb    = base + off; off += (size_t)5921 * 256;
    float* gxg    = base + off; off += (size_t)5730 * 768;
    float* gxc    = base + off; off += (size_t)5730 * 96;
    float* pboxb  = base + off; off += (size_t)5730 * 36;
    float* logitb = base + off; off += 5730;
    float* h2b    = base + off; off += 2 * 30 * 256;
    float* hc2b   = base + off; off += 2 * 30 * 32;
    float* parts  = base + off; off += 64;
    unsigned* wp  = (unsigned*)(base + off); off += 128 * 768;
    float* biasg  = base + off; off += 768;
    float* biasc  = base + off; off += 96;

    (void)hipMemsetAsync(d_ws, 0, 256, stream);  // barrier counter

    prep_w<<<(128 * 768 + 255) / 256, 256, 0, stream>>>(Wh_g, wp);
    prep_bias<<<1, 768, 0, stream>>>(bx_g, bh_g, bx_c, bh_c, biasg, biasc);

    gemm_tiled<false, true><<<dim3(4, 93), 256, 0, stream>>>(flow, W_rgb, b_rgb, rgb, 5921, 256, 4096);
    gemm_tiled<true, false><<<dim3(12, 90), 256, 0, stream>>>(rgb, Wx_g, biasg, gxg, 5730, 768, 512);
    precomp_kernel<<<5730, 256, 0, stream>>>(y, W_bb, b_bb, W_dd, b_dd, W_proj, b_proj,
                                             Wx_c, biasc, W_pbox, b_pbox, W_out, b_out,
                                             gxc, pboxb, logitb);
    seq_kernel<<<30, 768, 0, stream>>>(y, gxg, gxc, pboxb, logitb, wp, bh_g, Wh_c, bh_c,
                                       W_pbox, W_out, h2b, hc2b, bar, parts);
    reduce_kernel<<<1, 64, 0, stream>>>(parts, out);
}